// Round 10
// baseline (43.736 us; speedup 1.0000x reference)
//
#include <hip/hip_runtime.h>
#include <hip/hip_bf16.h>
#include <cstdint>

// VQ-VAE vector quantize: N=65536 vectors, D=64, K=512 codes.
// d_in[0]: inputs fp32 [65536,64], d_in[1]: embeddings fp32 [512,64]
// d_out: [0]=loss, [1..4194304]=latent (gathered fp32 embeddings)
//
// R10: DIAGNOSTIC build = R9 with the {stage+MFMA argmin} phase repeated
// REP=4 times (idempotent: fminf over identical packed distances; output
// bitwise identical). Purpose: S = (dur - 25.0)/3 isolates the phase cost,
// and pushes vq_main into the rocprof top-5 for a first clean counter read.

typedef __attribute__((ext_vector_type(8))) short bf16x8;
typedef __attribute__((ext_vector_type(4))) float f32x4;

#define REP 4

__device__ __forceinline__ short f2bf(float f) {
    uint32_t u = __builtin_bit_cast(uint32_t, f);
    u += 0x7FFFu + ((u >> 16) & 1u);   // round-to-nearest-even
    return (short)(u >> 16);
}

// ws layout (bytes):
//  [0, 65536)     : B fragments bf16(-e), [ct(32)][ks(2)][lane(64)] x 16B
//  [65536, 67584) : ee_t[512] fp32 = 0.5*||e_k||^2, TRANSPOSED [cb(16)][ct(32)]
//  [67584, 71680) : partials[1024] fp32
#define WS_EE   65536
#define WS_PART 67584

// ---------------- Kernel 1: setup (16 blocks x 256) ----------------
__global__ __launch_bounds__(256)
void vq_setup(const float* __restrict__ emb, char* __restrict__ ws) {
    const int tid = threadIdx.x, bid = blockIdx.x;
    bf16x8* bfrag = (bf16x8*)ws;
    float* eet = (float*)(ws + WS_EE);

    const int s = bid * 256 + tid;
    const int ct = s >> 7, ks = (s >> 6) & 1, ln = s & 63;
    const int code = (ct << 4) | (ln & 15);
    const int d0 = ks * 32 + ((ln >> 4) << 3);
    const float* src = emb + code * 64 + d0;
    float4 v0 = *(const float4*)src;
    float4 v1 = *(const float4*)(src + 4);
    bf16x8 b;
    b[0] = f2bf(-v0.x); b[1] = f2bf(-v0.y); b[2] = f2bf(-v0.z); b[3] = f2bf(-v0.w);
    b[4] = f2bf(-v1.x); b[5] = f2bf(-v1.y); b[6] = f2bf(-v1.z); b[7] = f2bf(-v1.w);
    bfrag[s] = b;

    if (tid < 32) {
        const int c = bid * 32 + tid;
        const float4* e4 = (const float4*)(emb + c * 64);
        float acc = 0.f;
        #pragma unroll
        for (int q = 0; q < 16; ++q) {
            float4 v = e4[q];
            acc = fmaf(v.x, v.x, fmaf(v.y, v.y, fmaf(v.z, v.z, fmaf(v.w, v.w, acc))));
        }
        eet[(c & 15) * 32 + (c >> 4)] = 0.5f * acc;   // transposed, pre-halved
    }
}

// ---------------- Kernel 2: main (1024 blocks x 256, 4 blocks/CU) ----------------
__global__ __launch_bounds__(256, 4)
void vq_main(const float* __restrict__ flat, const float* __restrict__ emb,
             char* __restrict__ ws, float* __restrict__ out) {
    __shared__ bf16x8 lbuf[2048];   // 32 KB pass buffer
    __shared__ float red[4];

    const int tid = threadIdx.x, bid = blockIdx.x;
    const int lane = tid & 63, wid = tid >> 6;
    const int cb = lane & 15, g = lane >> 4;
    const int rb = bid * 64 + wid * 16;   // wave's 16 rows
    const char* wsg = (const char*)ws;

    // ---- A loads: 1 M-tile x 2 k-steps x 2 float4 ----
    const float* asrc = flat + (long)(rb + cb) * 64 + (g << 3);
    float4 ar[2][2];
    ar[0][0] = *(const float4*)asrc;
    ar[0][1] = *(const float4*)(asrc + 4);
    ar[1][0] = *(const float4*)(asrc + 32);
    ar[1][1] = *(const float4*)(asrc + 36);

    // ---- issue pass-0 staging (32 KB, global_load_lds width 16, linear) ----
    {
        char* dst = (char*)lbuf;
        #pragma unroll
        for (int k = 0; k < 8; ++k) {
            const int off = (k * 256 + tid) * 16;
            __builtin_amdgcn_global_load_lds(
                (const __attribute__((address_space(1))) void*)(wsg + off),
                (__attribute__((address_space(3))) void*)(dst + off), 16, 0, 0);
        }
    }

    // ---- fp32 ||x||^2 partial + bf16 convert (overlaps staging) ----
    float xx = 0.f;
    #pragma unroll
    for (int ks = 0; ks < 2; ++ks)
        #pragma unroll
        for (int u = 0; u < 2; ++u) {
            float4 v = ar[ks][u];
            xx = fmaf(v.x, v.x, fmaf(v.y, v.y, fmaf(v.z, v.z, fmaf(v.w, v.w, xx))));
        }
    bf16x8 a[2];
    #pragma unroll
    for (int ks = 0; ks < 2; ++ks) {
        float4 v0 = ar[ks][0], v1 = ar[ks][1];
        bf16x8 f;
        f[0] = f2bf(v0.x); f[1] = f2bf(v0.y); f[2] = f2bf(v0.z); f[3] = f2bf(v0.w);
        f[4] = f2bf(v1.x); f[5] = f2bf(v1.y); f[6] = f2bf(v1.z); f[7] = f2bf(v1.w);
        a[ks] = f;
    }

    // ---- diagnostic: repeat the {stage + compute} phase REP times ----
    float pm[4];
    #pragma unroll
    for (int i = 0; i < 4; ++i) pm[i] = __builtin_bit_cast(float, 0x7F800000u);

    #pragma unroll 1
    for (int r = 0; r < REP; ++r) {
        #pragma unroll
        for (int p = 0; p < 2; ++p) {
            if (r || p) {
                __syncthreads();   // previous pass fully consumed
                char* dst = (char*)lbuf;
                const int gbase = p * 32768;
                #pragma unroll
                for (int k = 0; k < 8; ++k) {
                    const int off = (k * 256 + tid) * 16;
                    __builtin_amdgcn_global_load_lds(
                        (const __attribute__((address_space(1))) void*)(wsg + gbase + off),
                        (__attribute__((address_space(3))) void*)(dst + off), 16, 0, 0);
                }
            }
            // this pass's 16 half-norms for this lane's column class (L1-hit)
            const float4* hp = (const float4*)(wsg + WS_EE + cb * 128 + p * 64);
            float4 h0 = hp[0], h1 = hp[1], h2 = hp[2], h3 = hp[3];
            __syncthreads();       // staging complete (vmcnt(0) at barrier)

            #pragma unroll
            for (int ctl = 0; ctl < 16; ++ctl) {
                bf16x8 b0 = lbuf[ctl * 128 + lane];
                bf16x8 b1 = lbuf[ctl * 128 + 64 + lane];
                const int ct = p * 16 + ctl;
                const int colv = (ct << 4) | cb;
                const float4 hq = (ctl < 8) ? ((ctl < 4) ? h0 : h1) : ((ctl < 12) ? h2 : h3);
                const float h = (ctl & 3) == 0 ? hq.x : (ctl & 3) == 1 ? hq.y
                              : (ctl & 3) == 2 ? hq.z : hq.w;
                f32x4 acc = {h, h, h, h};        // 0.5||e||^2 - x.e   (B = -e)
                acc = __builtin_amdgcn_mfma_f32_16x16x32_bf16(a[0], b0, acc, 0, 0, 0);
                acc = __builtin_amdgcn_mfma_f32_16x16x32_bf16(a[1], b1, acc, 0, 0, 0);
                #pragma unroll
                for (int j = 0; j < 4; ++j) {
                    uint32_t dp = (__builtin_bit_cast(uint32_t, acc[j]) & 0xFFFFFE00u) | (uint32_t)colv;
                    pm[j] = fminf(pm[j], __builtin_bit_cast(float, dp));
                }
            }
        }
    }

    // ---- butterfly min over the 16 column-class lanes ----
    #pragma unroll
    for (int m = 1; m < 16; m <<= 1) {
        #pragma unroll
        for (int i = 0; i < 4; ++i)
            pm[i] = fminf(pm[i], __shfl_xor(pm[i], m, 64));
    }
    // post-butterfly: all 16 lanes of group g hold winners of rows rb+g*4+j

    // ---- loss partial: sum_rows( ||x||^2 + 2*unpack(pm_min) ) ----
    float t = xx;
    if (cb == 0) {
        #pragma unroll
        for (int j = 0; j < 4; ++j) {
            float v = __builtin_bit_cast(float, __builtin_bit_cast(uint32_t, pm[j]) & 0xFFFFFE00u);
            t = fmaf(2.f, v, t);
        }
    }
    #pragma unroll
    for (int m = 32; m; m >>= 1) t += __shfl_down(t, m, 64);
    if (lane == 0) red[wid] = t;

    // ---- epilogue: shuffle-free group-parallel gather + store ----
    float* ob = out + 1 + (long)rb * 64;
    const int l4 = cb * 4;
    #pragma unroll
    for (int j = 0; j < 4; ++j) {
        const int ix = (int)(__builtin_bit_cast(uint32_t, pm[j]) & 0x1FFu);
        float4 e = *(const float4*)(emb + ix * 64 + l4);
        const int ro = (g * 4 + j) * 64 + l4;
        ob[ro] = e.x; ob[ro + 1] = e.y; ob[ro + 2] = e.z; ob[ro + 3] = e.w;
    }

    __syncthreads();
    if (tid == 0) {
        float* part = (float*)(ws + WS_PART);
        part[bid] = red[0] + red[1] + red[2] + red[3];
    }
}

// ---------------- Kernel 3: deterministic final reduce (1 block) ----------------
__global__ __launch_bounds__(256)
void vq_loss(const float* __restrict__ partials, float* __restrict__ out) {
    __shared__ float red[4];
    const int tid = threadIdx.x;
    float acc = partials[tid] + partials[tid + 256] + partials[tid + 512] + partials[tid + 768];
    #pragma unroll
    for (int m = 32; m; m >>= 1) acc += __shfl_down(acc, m, 64);
    if ((tid & 63) == 0) red[tid >> 6] = acc;
    __syncthreads();
    // loss = 0.25*e_loss + q_loss = 1.25 * mse (forward)
    if (tid == 0) out[0] = 1.25f * (red[0] + red[1] + red[2] + red[3]) / 4194304.0f;
}

extern "C" void kernel_launch(void* const* d_in, const int* in_sizes, int n_in,
                              void* d_out, int out_size, void* d_ws, size_t ws_size,
                              hipStream_t stream) {
    const float* flat = (const float*)d_in[0];   // [65536,64]
    const float* emb  = (const float*)d_in[1];   // [512,64]
    float* out = (float*)d_out;
    char* ws = (char*)d_ws;

    vq_setup<<<16, 256, 0, stream>>>(emb, ws);
    vq_main<<<1024, 256, 0, stream>>>(flat, emb, ws, out);
    vq_loss<<<1, 256, 0, stream>>>((const float*)(ws + WS_PART), out);
}

// Round 11
// 24.251 us; speedup vs baseline: 1.8035x; 1.8035x over previous
//
#include <hip/hip_runtime.h>
#include <hip/hip_bf16.h>
#include <cstdint>

// VQ-VAE vector quantize: N=65536 vectors, D=64, K=512 codes.
// d_in[0]: inputs fp32 [65536,64], d_in[1]: embeddings fp32 [512,64]
// d_out: [0]=loss, [1..4194304]=latent (gathered fp32 embeddings)
//
// R11: codebook-in-VGPRs structure. R10 diagnostic showed the old
// codebook-through-LDS loop costs 6.2 us/phase, dominated by 256 MB of
// ds_read re-reads. Now: each wave holds a 128-code slice in 64 VGPRs
// (loaded once), loops over 4 row-tiles staged in a 4 KB LDS buffer.
// Cross-wave argmin combine via LDS slots + epilogue fminf (no atomics).

typedef __attribute__((ext_vector_type(8))) short bf16x8;
typedef __attribute__((ext_vector_type(4))) float f32x4;

__device__ __forceinline__ short f2bf(float f) {
    uint32_t u = __builtin_bit_cast(uint32_t, f);
    u += 0x7FFFu + ((u >> 16) & 1u);   // round-to-nearest-even
    return (short)(u >> 16);
}

// ws layout (bytes):
//  [0, 65536)     : B fragments bf16(-e), [ct(32)][ks(2)][lane(64)] x 16B
//  [65536, 67584) : ee_t[512] fp32 = 0.5*||e_k||^2, TRANSPOSED [cb(16)][ct(32)]
//  [67584, 71680) : partials[1024] fp32
#define WS_EE   65536
#define WS_PART 67584

// ---------------- Kernel 1: setup (16 blocks x 256) ----------------
__global__ __launch_bounds__(256)
void vq_setup(const float* __restrict__ emb, char* __restrict__ ws) {
    const int tid = threadIdx.x, bid = blockIdx.x;
    bf16x8* bfrag = (bf16x8*)ws;
    float* eet = (float*)(ws + WS_EE);

    const int s = bid * 256 + tid;
    const int ct = s >> 7, ks = (s >> 6) & 1, ln = s & 63;
    const int code = (ct << 4) | (ln & 15);
    const int d0 = ks * 32 + ((ln >> 4) << 3);
    const float* src = emb + code * 64 + d0;
    float4 v0 = *(const float4*)src;
    float4 v1 = *(const float4*)(src + 4);
    bf16x8 b;
    b[0] = f2bf(-v0.x); b[1] = f2bf(-v0.y); b[2] = f2bf(-v0.z); b[3] = f2bf(-v0.w);
    b[4] = f2bf(-v1.x); b[5] = f2bf(-v1.y); b[6] = f2bf(-v1.z); b[7] = f2bf(-v1.w);
    bfrag[s] = b;

    if (tid < 32) {
        const int c = bid * 32 + tid;
        const float4* e4 = (const float4*)(emb + c * 64);
        float acc = 0.f;
        #pragma unroll
        for (int q = 0; q < 16; ++q) {
            float4 v = e4[q];
            acc = fmaf(v.x, v.x, fmaf(v.y, v.y, fmaf(v.z, v.z, fmaf(v.w, v.w, acc))));
        }
        eet[(c & 15) * 32 + (c >> 4)] = 0.5f * acc;   // transposed, pre-halved
    }
}

// ---------------- Kernel 2: main (1024 blocks x 256) ----------------
// Block owns 64 rows. Wave w holds codes [w*128, w*128+128) in VGPRs and
// computes its partial argmin for ALL 64 rows; combine across waves in LDS.
__global__ __launch_bounds__(256)
void vq_main(const float* __restrict__ flat, const float* __restrict__ emb,
             char* __restrict__ ws, float* __restrict__ out) {
    __shared__ bf16x8 albuf[4][2][64];   // 4 KB  [rt][ks][lane] A fragments
    __shared__ float  cmb[4][64];        // 1 KB  [wave][row] packed partial min
    __shared__ float  red[4];

    const int tid = threadIdx.x, bid = blockIdx.x;
    const int lane = tid & 63, wid = tid >> 6;
    const int cb = lane & 15, g = lane >> 4;
    const int rb = bid * 64;             // block's 64 rows
    const char* wsg = (const char*)ws;

    // ---- A loads: wave stages its OWN 16 rows (row-tile wid) ----
    const float* asrc = flat + (long)(rb + wid * 16 + cb) * 64 + (g << 3);
    float4 ar00 = *(const float4*)asrc;
    float4 ar01 = *(const float4*)(asrc + 4);
    float4 ar10 = *(const float4*)(asrc + 32);
    float4 ar11 = *(const float4*)(asrc + 36);

    // ---- B slice: wave's 8 col-tiles (128 codes) -> 64 VGPRs, loaded once ----
    const bf16x8* wsb = (const bf16x8*)wsg;
    bf16x8 bv[8][2];
    #pragma unroll
    for (int c = 0; c < 8; ++c) {
        bv[c][0] = wsb[(wid * 8 + c) * 128 + lane];
        bv[c][1] = wsb[(wid * 8 + c) * 128 + 64 + lane];
    }

    // ---- half-norms for this wave's 8 col-tiles, this lane's col class ----
    float hvv[8];
    {
        const float4* hp = (const float4*)(wsg + WS_EE + cb * 128 + wid * 32);
        float4 h0 = hp[0], h1 = hp[1];
        hvv[0] = h0.x; hvv[1] = h0.y; hvv[2] = h0.z; hvv[3] = h0.w;
        hvv[4] = h1.x; hvv[5] = h1.y; hvv[6] = h1.z; hvv[7] = h1.w;
    }

    // ---- ||x||^2 partial (wave's own rows only; disjoint across waves) ----
    float xx = 0.f;
    {
        float4 v;
        v = ar00; xx = fmaf(v.x, v.x, fmaf(v.y, v.y, fmaf(v.z, v.z, fmaf(v.w, v.w, xx))));
        v = ar01; xx = fmaf(v.x, v.x, fmaf(v.y, v.y, fmaf(v.z, v.z, fmaf(v.w, v.w, xx))));
        v = ar10; xx = fmaf(v.x, v.x, fmaf(v.y, v.y, fmaf(v.z, v.z, fmaf(v.w, v.w, xx))));
        v = ar11; xx = fmaf(v.x, v.x, fmaf(v.y, v.y, fmaf(v.z, v.z, fmaf(v.w, v.w, xx))));
    }

    // ---- convert own A rows to bf16 fragments and share via LDS ----
    {
        bf16x8 f;
        f[0] = f2bf(ar00.x); f[1] = f2bf(ar00.y); f[2] = f2bf(ar00.z); f[3] = f2bf(ar00.w);
        f[4] = f2bf(ar01.x); f[5] = f2bf(ar01.y); f[6] = f2bf(ar01.z); f[7] = f2bf(ar01.w);
        albuf[wid][0][lane] = f;
        f[0] = f2bf(ar10.x); f[1] = f2bf(ar10.y); f[2] = f2bf(ar10.z); f[3] = f2bf(ar10.w);
        f[4] = f2bf(ar11.x); f[5] = f2bf(ar11.y); f[6] = f2bf(ar11.z); f[7] = f2bf(ar11.w);
        albuf[wid][1][lane] = f;
    }
    __syncthreads();

    // ---- main loop: 4 row-tiles x 8 col-tiles, B from VGPRs ----
    float pm[4][4];
    #pragma unroll
    for (int rt = 0; rt < 4; ++rt)
        #pragma unroll
        for (int j = 0; j < 4; ++j) pm[rt][j] = __builtin_bit_cast(float, 0x7F800000u);

    #pragma unroll
    for (int rt = 0; rt < 4; ++rt) {
        bf16x8 a0 = albuf[rt][0][lane];
        bf16x8 a1 = albuf[rt][1][lane];
        #pragma unroll
        for (int c = 0; c < 8; ++c) {
            const float h = hvv[c];
            const int colv = ((wid * 8 + c) << 4) | cb;
            f32x4 acc = {h, h, h, h};        // 0.5||e||^2 - x.e   (B = -e)
            acc = __builtin_amdgcn_mfma_f32_16x16x32_bf16(a0, bv[c][0], acc, 0, 0, 0);
            acc = __builtin_amdgcn_mfma_f32_16x16x32_bf16(a1, bv[c][1], acc, 0, 0, 0);
            #pragma unroll
            for (int j = 0; j < 4; ++j) {
                uint32_t dp = (__builtin_bit_cast(uint32_t, acc[j]) & 0xFFFFFE00u) | (uint32_t)colv;
                pm[rt][j] = fminf(pm[rt][j], __builtin_bit_cast(float, dp));
            }
        }
    }

    // ---- butterfly min over the 16 column-class lanes (per row-tile) ----
    #pragma unroll
    for (int m = 1; m < 16; m <<= 1) {
        #pragma unroll
        for (int rt = 0; rt < 4; ++rt)
            #pragma unroll
            for (int j = 0; j < 4; ++j)
                pm[rt][j] = fminf(pm[rt][j], __shfl_xor(pm[rt][j], m, 64));
    }
    // group g now holds this wave's partial winner for rows rt*16 + g*4 + j
    if (cb == 0) {
        #pragma unroll
        for (int rt = 0; rt < 4; ++rt)
            #pragma unroll
            for (int j = 0; j < 4; ++j)
                cmb[wid][rt * 16 + g * 4 + j] = pm[rt][j];
    }
    __syncthreads();

    // ---- epilogue: cross-wave combine + gather + store + loss ----
    // thread t: row = t>>2 (0..63), seg = t&3 (16 floats each)
    const int row = tid >> 2, seg = tid & 3;
    const float mn = fminf(fminf(cmb[0][row], cmb[1][row]),
                           fminf(cmb[2][row], cmb[3][row]));
    const uint32_t mbits = __builtin_bit_cast(uint32_t, mn);
    const int ix = (int)(mbits & 0x1FFu);

    const float4* esrc = (const float4*)(emb + ix * 64 + seg * 16);
    float4 e0 = esrc[0], e1 = esrc[1], e2 = esrc[2], e3 = esrc[3];
    float* ob = out + 1 + (long)(rb + row) * 64 + seg * 16;
    ob[0]  = e0.x; ob[1]  = e0.y; ob[2]  = e0.z; ob[3]  = e0.w;
    ob[4]  = e1.x; ob[5]  = e1.y; ob[6]  = e1.z; ob[7]  = e1.w;
    ob[8]  = e2.x; ob[9]  = e2.y; ob[10] = e2.z; ob[11] = e2.w;
    ob[12] = e3.x; ob[13] = e3.y; ob[14] = e3.z; ob[15] = e3.w;

    // loss partial: xx (per-lane, disjoint rows) + 2*unpack(min) once per row
    float t = xx;
    if (seg == 0) {
        float v = __builtin_bit_cast(float, mbits & 0xFFFFFE00u);
        t = fmaf(2.f, v, t);
    }
    #pragma unroll
    for (int m = 32; m; m >>= 1) t += __shfl_down(t, m, 64);
    if (lane == 0) red[wid] = t;
    __syncthreads();
    if (tid == 0) {
        float* part = (float*)(ws + WS_PART);
        part[bid] = red[0] + red[1] + red[2] + red[3];
    }
}

// ---------------- Kernel 3: deterministic final reduce (1 block) ----------------
__global__ __launch_bounds__(256)
void vq_loss(const float* __restrict__ partials, float* __restrict__ out) {
    __shared__ float red[4];
    const int tid = threadIdx.x;
    float acc = partials[tid] + partials[tid + 256] + partials[tid + 512] + partials[tid + 768];
    #pragma unroll
    for (int m = 32; m; m >>= 1) acc += __shfl_down(acc, m, 64);
    if ((tid & 63) == 0) red[tid >> 6] = acc;
    __syncthreads();
    // loss = 0.25*e_loss + q_loss = 1.25 * mse (forward)
    if (tid == 0) out[0] = 1.25f * (red[0] + red[1] + red[2] + red[3]) / 4194304.0f;
}

extern "C" void kernel_launch(void* const* d_in, const int* in_sizes, int n_in,
                              void* d_out, int out_size, void* d_ws, size_t ws_size,
                              hipStream_t stream) {
    const float* flat = (const float*)d_in[0];   // [65536,64]
    const float* emb  = (const float*)d_in[1];   // [512,64]
    float* out = (float*)d_out;
    char* ws = (char*)d_ws;

    vq_setup<<<16, 256, 0, stream>>>(emb, ws);
    vq_main<<<1024, 256, 0, stream>>>(flat, emb, ws, out);
    vq_loss<<<1, 256, 0, stream>>>((const float*)(ws + WS_PART), out);
}